// Round 4
// baseline (143.417 us; speedup 1.0000x reference)
//
#include <hip/hip_runtime.h>
#include <math.h>

#define S_LEN 2049
#define P_LEN 2048
#define EMB 512
#define NH 8
#define HD 64
#define SCALE 0.125f

typedef _Float16 f16x8 __attribute__((ext_vector_type(8)));
typedef float f32x4 __attribute__((ext_vector_type(4)));
typedef unsigned short u16x8 __attribute__((ext_vector_type(8)));

__device__ inline unsigned short f2h(float f) {
  _Float16 h = (_Float16)f;  // RNE
  return __builtin_bit_cast(unsigned short, h);
}
__device__ inline float h2f(unsigned short u) {
  return (float)__builtin_bit_cast(_Float16, u);
}

// async global->LDS, 16B per lane; LDS dest = wave-uniform base + lane*16
__device__ inline void gld16(const unsigned* g, unsigned* l) {
  __builtin_amdgcn_global_load_lds(
      (const __attribute__((address_space(1))) unsigned*)g,
      (__attribute__((address_space(3))) unsigned*)l, 16, 0, 0);
}

// fused fp32 -> fp16 converter for the three operands (x, qkv_w, out_w).
__global__ __launch_bounds__(256) void cvt3_f16(
    const float* __restrict__ s0, unsigned short* __restrict__ d0, int n0,
    const float* __restrict__ s1, unsigned short* __restrict__ d1, int n1,
    const float* __restrict__ s2, unsigned short* __restrict__ d2, int n2) {
  int idx = (blockIdx.x * 256 + threadIdx.x) * 8;
  const float* s;
  unsigned short* d;
  int off;
  if (idx < n0) {
    s = s0; d = d0; off = idx;
  } else if (idx < n0 + n1) {
    s = s1; d = d1; off = idx - n0;
  } else if (idx < n0 + n1 + n2) {
    s = s2; d = d2; off = idx - n0 - n1;
  } else {
    return;
  }
  float4 f0 = *(const float4*)(s + off);
  float4 f1 = *(const float4*)(s + off + 4);
  float ff[8] = {f0.x, f0.y, f0.z, f0.w, f1.x, f1.y, f1.z, f1.w};
  u16x8 vh;
#pragma unroll
  for (int e = 0; e < 8; e++) vh[e] = f2h(ff[e]);
  *(u16x8*)(d + off) = vh;
}

// Plain fp16 GEMM, m97 structure (single-buffer, 2 barriers/K-step), 2x2 wave
// tiling: C = A[M,KP] @ B[N,KP]^T + bias.
// R1 lesson: dbuf (2x LDS) regressed. R2 lesson: 128x128 tile (396 blocks,
// 1.5/CU) regressed. 64-row tiles + 780/520 blocks is the verified optimum
// for this short-K (8 K-step) shape.
template <int BM, int BN, bool F16OUT>
__global__ __launch_bounds__(256) void gemm_f16(
    const unsigned short* __restrict__ A, const unsigned short* __restrict__ B,
    const float* __restrict__ bias, void* __restrict__ Cv, int M, int N,
    int KP) {
  constexpr int BK = 64;
  __shared__ __align__(16) unsigned short As[BM * BK];
  __shared__ __align__(16) unsigned short Bs[BN * BK];
  const int t = threadIdx.x;
  const int lane = t & 63, wv = t >> 6;
  const int m0 = blockIdx.x * BM, n0 = blockIdx.y * BN;
  constexpr int WM = BM / 2, WN = BN / 2;
  constexpr int RM = WM / 16, RN = WN / 16;
  const int wm = wv & 1, wn = wv >> 1;
  const int lm = lane & 15, lq = lane >> 4;

  f32x4 acc[RM][RN];
#pragma unroll
  for (int i = 0; i < RM; i++)
#pragma unroll
    for (int j = 0; j < RN; j++) acc[i][j] = (f32x4){0.f, 0.f, 0.f, 0.f};

  const int lr = lane >> 3;
  const int lc = (lane & 7) ^ lr;  // XOR-swizzled source chunk (bank spread)

  const unsigned* aptr[BM / 32];
#pragma unroll
  for (int p = 0; p < BM / 32; p++) {
    int ra = wv * (BM / 4) + p * 8 + lr;
    int gr = m0 + ra;
    gr = gr < M ? gr : M - 1;  // clamp source (epilogue store is guarded)
    aptr[p] = (const unsigned*)(A + (size_t)gr * KP + lc * 8);
  }
  const unsigned* bptr[BN / 32];
#pragma unroll
  for (int p = 0; p < BN / 32; p++) {
    int rb = wv * (BN / 4) + p * 8 + lr;
    bptr[p] = (const unsigned*)(B + (size_t)(n0 + rb) * KP + lc * 8);
  }

  for (int kt = 0; kt < KP; kt += BK) {
    __syncthreads();
#pragma unroll
    for (int p = 0; p < BM / 32; p++)
      gld16(aptr[p] + (kt >> 1), (unsigned*)&As[(wv * (BM / 4) + p * 8) * BK]);
#pragma unroll
    for (int p = 0; p < BN / 32; p++)
      gld16(bptr[p] + (kt >> 1), (unsigned*)&Bs[(wv * (BN / 4) + p * 8) * BK]);
    __syncthreads();

    f16x8 fa[2][RM], fb[2][RN];
#pragma unroll
    for (int kk = 0; kk < 2; kk++) {
      int ch = ((kk * 4 + lq) ^ (lm & 7)) * 8;
#pragma unroll
      for (int mi = 0; mi < RM; mi++) {
        int ra = wm * WM + mi * 16 + lm;
        fa[kk][mi] = *(const f16x8*)&As[ra * BK + ch];
      }
#pragma unroll
      for (int ni = 0; ni < RN; ni++) {
        int rb = wn * WN + ni * 16 + lm;
        fb[kk][ni] = *(const f16x8*)&Bs[rb * BK + ch];
      }
    }
#pragma unroll
    for (int kk = 0; kk < 2; kk++)
#pragma unroll
      for (int mi = 0; mi < RM; mi++)
#pragma unroll
        for (int ni = 0; ni < RN; ni++)
          acc[mi][ni] = __builtin_amdgcn_mfma_f32_16x16x32_f16(
              fa[kk][mi], fb[kk][ni], acc[mi][ni], 0, 0, 0);
  }

  // C/D layout: col=lane&15 (=n), row=(lane>>4)*4+reg (=m)  [m89/m91]
#pragma unroll
  for (int ni = 0; ni < RN; ni++) {
    int n = n0 + wn * WN + ni * 16 + lm;
    float bv = bias[n];
#pragma unroll
    for (int mi = 0; mi < RM; mi++)
#pragma unroll
      for (int r = 0; r < 4; r++) {
        int m = m0 + wm * WM + mi * 16 + lq * 4 + r;
        if (m < M) {
          float val = acc[mi][ni][r] + bv;
          if constexpr (F16OUT)
            ((unsigned short*)Cv)[(size_t)m * N + n] = f2h(val);
          else
            ((float*)Cv)[(size_t)m * N + n] = val;
        }
      }
  }
}

// MFMA flash-window attention over fp16 qkv + fused CLS attention.
// grid = (17, NH, 2*B): blockIdx.x==0 -> CLS blocks (par==0 only; one block
// per (b,h) computes the full 2049-key cls attention with online softmax —
// replaces the former cls_part_k/split-K/combine chain entirely).
// blockIdx.x 1..16 -> patch blocks (qc0 = (qb-1)*64), unchanged structure.
// Zeroing is PRECISE (R3, verified win): only read-but-never-staged regions.
__global__ __launch_bounds__(256) void patch_attn3(
    const unsigned short* __restrict__ qkv16,
    unsigned short* __restrict__ Aatt) {
  constexpr int LDK = 72;   // ushort stride for Ks (144 B rows, 16B-aligned)
  constexpr int LDT = 168;  // ushort stride for Vt/Ps
  __shared__ __align__(16) unsigned short Ks[144 * LDK];  // 20.25 KB
  __shared__ __align__(16) unsigned short Vt[64 * LDT];   // 21 KB
  __shared__ __align__(16) unsigned short Ps[64 * LDT];   // 21 KB

  const int t = threadIdx.x;
  const int lane = t & 63, wv = t >> 6;
  const int lm = lane & 15, lq = lane >> 4;
  const int qb = blockIdx.x;  // 0 = cls, 1..16 = patch
  const int h = blockIdx.y;
  const int par = blockIdx.z & 1, b = blockIdx.z >> 1;
  const unsigned short* base = qkv16 + (size_t)b * S_LEN * 1536;

  if (qb == 0) {
    // ================= CLS attention block =================
    if (par == 1) return;  // 16 active blocks total (b,h)
    // lane layout: kidx = lane>>3 (8 keys/wave/iter), c = lane&7 (dim group)
    const int kidx = lane >> 3, c = lane & 7, d0 = c * 8;
    // q fragment (8 dims), SCALE folded
    float qv[8];
    {
      f16x8 qh = *(const f16x8*)(base + h * 64 + d0);
#pragma unroll
      for (int i = 0; i < 8; i++) qv[i] = (float)qh[i] * SCALE;
    }
    float m = -1e30f, l = 0.f, o[8];
#pragma unroll
    for (int i = 0; i < 8; i++) o[i] = 0.f;

    // 32 keys per iteration across 4 waves; 65 iterations cover 2049 keys
    for (int it = 0; it < 65; it++) {
      int j = it * 32 + wv * 8 + kidx;
      bool valid = j < S_LEN;
      f16x8 kh, vh;
      if (valid) {
        const unsigned short* row = base + (size_t)j * 1536 + 512 + h * 64;
        kh = *(const f16x8*)(row + d0);
        vh = *(const f16x8*)(row + 512 + d0);
      }
      float dp = 0.f;
      if (valid) {
#pragma unroll
        for (int i = 0; i < 8; i++) dp += qv[i] * (float)kh[i];
      }
      // reduce over dim groups (bits 0..2)
#pragma unroll
      for (int off = 1; off < 8; off <<= 1) dp += __shfl_xor(dp, off, 64);
      float s = valid ? dp : -1e30f;
      // wave max over the 8 keys (bits 3..5)
      float cmax = s;
#pragma unroll
      for (int off = 8; off < 64; off <<= 1)
        cmax = fmaxf(cmax, __shfl_xor(cmax, off, 64));
      float mn = fmaxf(m, cmax);
      float sc = __expf(m - mn);
      float e = valid ? __expf(s - mn) : 0.f;
      float esum = e;
#pragma unroll
      for (int off = 8; off < 64; off <<= 1) esum += __shfl_xor(esum, off, 64);
      l = l * sc + esum;
#pragma unroll
      for (int i = 0; i < 8; i++)
        o[i] = o[i] * sc + (valid ? e * (float)vh[i] : 0.f);
      m = mn;
    }
    // sum o over the 8 kidx lanes (bits 3..5)
#pragma unroll
    for (int i = 0; i < 8; i++) {
#pragma unroll
      for (int off = 8; off < 64; off <<= 1) o[i] += __shfl_xor(o[i], off, 64);
    }
    // cross-wave combine via LDS (reuse Ks as float scratch)
    float* SF = (float*)Ks;  // [4][64] o + [4] m + [4] l
    if (kidx == 0) {
#pragma unroll
      for (int i = 0; i < 8; i++) SF[wv * 64 + d0 + i] = o[i];
    }
    if (lane == 0) {
      SF[256 + wv] = m;
      SF[260 + wv] = l;
    }
    __syncthreads();
    if (t < 64) {
      float M = -1e30f;
#pragma unroll
      for (int i = 0; i < 4; i++) M = fmaxf(M, SF[256 + i]);
      float L = 0.f, O = 0.f;
#pragma unroll
      for (int i = 0; i < 4; i++) {
        float cexp = __expf(SF[256 + i] - M);
        L += SF[260 + i] * cexp;
        O += SF[i * 64 + t] * cexp;
      }
      Aatt[(size_t)b * S_LEN * 512 + h * HD + t] = f2h(O / L);
    }
    return;
  }

  // ================= patch attention block =================
  const int qc0 = (qb - 1) * 64;

  // ---- precise zero of read-but-never-staged LDS regions ----
  {
    uint4 z = {0, 0, 0, 0};
    // Ks rows 129..143, cols 0..63 (QK^T reads rows up to 143): 120 x 16B
    if (t < 120) {
      int r = 129 + (t >> 3), c = (t & 7) * 8;
      *(uint4*)&Ks[r * LDK + c] = z;
    }
    // Vt cols 128..159, rows 0..63 (PV K=160; col 128 re-staged below): 256
    {
      int r = t >> 2, c = 128 + (t & 3) * 8;
      *(uint4*)&Vt[r * LDT + c] = z;
    }
    // Ps cols 144..159, rows 0..63 (softmax writes only cols 0..143): 128
    if (t < 128) {
      int r = t >> 1, c = 144 + (t & 1) * 8;
      *(uint4*)&Ps[r * LDT + c] = z;
    }
  }
  __syncthreads();

  // ---- stage K (direct fp16 copy): window rows 0..127, cls row 128 ----
  {
    int rr = t >> 4;
    int cc = (t & 15) * 4;  // 4 halves (8 B) per thread
#pragma unroll
    for (int pass = 0; pass < 8; pass++) {
      int r = pass * 16 + rr;
      int jc = qc0 - 32 + r;
      uint2 kv = {0, 0};
      if ((unsigned)jc < 1024u)
        kv = *(const uint2*)(base + (size_t)(1 + 2 * jc + par) * 1536 + 512 +
                             h * 64 + cc);
      *(uint2*)&Ks[r * LDK + cc] = kv;
    }
    if (rr == 0)
      *(uint2*)&Ks[128 * LDK + cc] =
          *(const uint2*)(base + 512 + h * 64 + cc);
  }
  // ---- stage V transposed: Vt[d][jl] via half-pair repack ----
#pragma unroll
  for (int pass = 0; pass < 4; pass++) {
    int task = pass * 256 + t;
    int jp = task >> 4;        // jl pair 0..63
    int d0 = (task & 15) * 4;  // dim base
    int jc0 = qc0 - 32 + 2 * jp;
    uint2 a = {0, 0}, c = {0, 0};
    if ((unsigned)jc0 < 1024u)
      a = *(const uint2*)(base + (size_t)(1 + 2 * jc0 + par) * 1536 + 1024 +
                          h * 64 + d0);
    if ((unsigned)(jc0 + 1) < 1024u)
      c = *(const uint2*)(base + (size_t)(1 + 2 * (jc0 + 1) + par) * 1536 +
                          1024 + h * 64 + d0);
    *(unsigned*)&Vt[(d0 + 0) * LDT + 2 * jp] = (a.x & 0xffffu) | (c.x << 16);
    *(unsigned*)&Vt[(d0 + 1) * LDT + 2 * jp] = (a.x >> 16) | (c.x & 0xffff0000u);
    *(unsigned*)&Vt[(d0 + 2) * LDT + 2 * jp] = (a.y & 0xffffu) | (c.y << 16);
    *(unsigned*)&Vt[(d0 + 3) * LDT + 2 * jp] = (a.y >> 16) | (c.y & 0xffff0000u);
  }
  if (t < 64) Vt[t * LDT + 128] = base[1024 + h * 64 + t];  // cls V col

  // ---- Q fragment: direct f16x8 loads (A-frag: m=lane&15, k=quad*8+j) ----
  const int qi = wv * 16 + lm;
  const unsigned short* qg =
      base + (size_t)(1 + 2 * (qc0 + qi) + par) * 1536 + h * 64;
  f16x8 qf[2];
  qf[0] = *(const f16x8*)&qg[lq * 8];
  qf[1] = *(const f16x8*)&qg[32 + lq * 8];
  __syncthreads();

  // ---- S = Q·K^T : 9 N-tiles of 16 cols ----
  f32x4 s[9];
#pragma unroll
  for (int nt = 0; nt < 9; nt++) s[nt] = (f32x4){0.f, 0.f, 0.f, 0.f};
#pragma unroll
  for (int nt = 0; nt < 9; nt++) {
#pragma unroll
    for (int kk = 0; kk < 2; kk++) {
      f16x8 kb = *(const f16x8*)&Ks[(nt * 16 + lm) * LDK + kk * 32 + lq * 8];
      s[nt] =
          __builtin_amdgcn_mfma_f32_16x16x32_f16(qf[kk], kb, s[nt], 0, 0, 0);
    }
  }

  // ---- masked softmax per row; SCALE applied here (post-MFMA, fp32) ----
  float L[4];
#pragma unroll
  for (int r = 0; r < 4; r++) {
    int qrow = wv * 16 + lq * 4 + r;  // query index within 64-chunk
    float sv[9];
    float mx = -1e30f;
#pragma unroll
    for (int nt = 0; nt < 9; nt++) {
      int jl = nt * 16 + lm;
      bool valid =
          (jl == 128) ||
          (jl < 128 && jl >= qrow && jl <= qrow + 64 &&
           (unsigned)(qc0 - 32 + jl) < 1024u);
      sv[nt] = valid ? s[nt][r] * SCALE : -1e30f;
      mx = fmaxf(mx, sv[nt]);
    }
#pragma unroll
    for (int off = 1; off < 16; off <<= 1)
      mx = fmaxf(mx, __shfl_xor(mx, off, 16));
    float l = 0.f;
#pragma unroll
    for (int nt = 0; nt < 9; nt++) {
      float e = __expf(sv[nt] - mx);
      l += e;
      Ps[qrow * LDT + nt * 16 + lm] = f2h(e);
    }
#pragma unroll
    for (int off = 1; off < 16; off <<= 1) l += __shfl_xor(l, off, 16);
    L[r] = l;
  }
  __syncthreads();

  // ---- O = P·V : A=Ps rows (m=query), B=Vt rows (n=d), K=160 ----
  f32x4 oa[4];
#pragma unroll
  for (int nt = 0; nt < 4; nt++) oa[nt] = (f32x4){0.f, 0.f, 0.f, 0.f};
#pragma unroll
  for (int kc = 0; kc < 5; kc++) {
    f16x8 pa = *(const f16x8*)&Ps[(wv * 16 + lm) * LDT + kc * 32 + lq * 8];
#pragma unroll
    for (int nt = 0; nt < 4; nt++) {
      f16x8 vb = *(const f16x8*)&Vt[(nt * 16 + lm) * LDT + kc * 32 + lq * 8];
      oa[nt] = __builtin_amdgcn_mfma_f32_16x16x32_f16(pa, vb, oa[nt], 0, 0, 0);
    }
  }

  // ---- epilogue: normalize, write fp16 into Aatt[*, 512] ----
#pragma unroll
  for (int r = 0; r < 4; r++) {
    float inv = 1.f / L[r];
    int qrow = wv * 16 + lq * 4 + r;
    int pp = 2 * (qc0 + qrow) + par;
    unsigned short* ab = Aatt + ((size_t)b * S_LEN + 1 + pp) * 512 + h * 64;
#pragma unroll
    for (int nt = 0; nt < 4; nt++) ab[nt * 16 + lm] = f2h(oa[nt][r] * inv);
  }
}

extern "C" void kernel_launch(void* const* d_in, const int* in_sizes, int n_in,
                              void* d_out, int out_size, void* d_ws,
                              size_t ws_size, hipStream_t stream) {
  const float* x = (const float*)d_in[0];
  const float* qkv_w = (const float*)d_in[1];
  const float* qkv_b = (const float*)d_in[2];
  const float* out_w = (const float*)d_in[3];
  const float* out_b = (const float*)d_in[4];
  float* out = (float*)d_out;

  const int M = 2 * S_LEN;  // 4098

  // ws layout (cls split-K buffers removed in R4; offsets kept stable)
  unsigned short* Xp = (unsigned short*)((float*)d_ws + 33792);  // 4098*512
  unsigned short* Wq = Xp + (size_t)M * 512;                     // 1536*512
  unsigned short* Wo = Wq + (size_t)1536 * 512;                  // 512*512
  unsigned short* Aatt = Wo + (size_t)512 * 512;                 // 4098*512
  unsigned short* qkv16 = Aatt + (size_t)M * 512;                // 4098*1536

  const int n0 = M * EMB;       // 2098176
  const int n1 = 1536 * EMB;    // 786432
  const int n2 = EMB * EMB;     // 262144
  int cvt_blocks = ((n0 + n1 + n2) / 8 + 255) / 256;
  cvt3_f16<<<cvt_blocks, 256, 0, stream>>>(x, Xp, n0, qkv_w, Wq, n1, out_w, Wo,
                                           n2);

  // QKV projection: fp16 GEMM K=512, fp16 output (R0-verified config)
  dim3 gq((M + 63) / 64, 1536 / 128);  // 65 x 12 = 780 blocks
  gemm_f16<64, 128, true><<<gq, 256, 0, stream>>>(Xp, Wq, qkv_b, qkv16, M,
                                                  1536, 512);

  // fused attention: cls blocks (x==0) + patch blocks (x==1..16)
  patch_attn3<<<dim3(17, NH, 4), 256, 0, stream>>>(qkv16, Aatt);

  // Output projection: fp16 GEMM K=512, fp32 output (R0-verified config)
  dim3 go((M + 63) / 64, EMB / 64);  // 65 x 8 = 520 blocks
  gemm_f16<64, 64, false><<<go, 256, 0, stream>>>(Aatt, Wo, out_b, out, M, EMB,
                                                  512);
}

// Round 6
// 122.383 us; speedup vs baseline: 1.1719x; 1.1719x over previous
//
#include <hip/hip_runtime.h>
#include <math.h>

#define S_LEN 2049
#define P_LEN 2048
#define EMB 512
#define NH 8
#define HD 64
#define SCALE 0.125f

typedef _Float16 f16x8 __attribute__((ext_vector_type(8)));
typedef float f32x4 __attribute__((ext_vector_type(4)));
typedef unsigned short u16x8 __attribute__((ext_vector_type(8)));

__device__ inline unsigned short f2h(float f) {
  _Float16 h = (_Float16)f;  // RNE
  return __builtin_bit_cast(unsigned short, h);
}
__device__ inline float h2f(unsigned short u) {
  return (float)__builtin_bit_cast(_Float16, u);
}

// async global->LDS, 16B per lane; LDS dest = wave-uniform base + lane*16
__device__ inline void gld16(const unsigned* g, unsigned* l) {
  __builtin_amdgcn_global_load_lds(
      (const __attribute__((address_space(1))) unsigned*)g,
      (__attribute__((address_space(3))) unsigned*)l, 16, 0, 0);
}

// fused fp32 -> fp16 converter for the three operands (x, qkv_w, out_w).
__global__ __launch_bounds__(256) void cvt3_f16(
    const float* __restrict__ s0, unsigned short* __restrict__ d0, int n0,
    const float* __restrict__ s1, unsigned short* __restrict__ d1, int n1,
    const float* __restrict__ s2, unsigned short* __restrict__ d2, int n2) {
  int idx = (blockIdx.x * 256 + threadIdx.x) * 8;
  const float* s;
  unsigned short* d;
  int off;
  if (idx < n0) {
    s = s0; d = d0; off = idx;
  } else if (idx < n0 + n1) {
    s = s1; d = d1; off = idx - n0;
  } else if (idx < n0 + n1 + n2) {
    s = s2; d = d2; off = idx - n0 - n1;
  } else {
    return;
  }
  float4 f0 = *(const float4*)(s + off);
  float4 f1 = *(const float4*)(s + off + 4);
  float ff[8] = {f0.x, f0.y, f0.z, f0.w, f1.x, f1.y, f1.z, f1.w};
  u16x8 vh;
#pragma unroll
  for (int e = 0; e < 8; e++) vh[e] = f2h(ff[e]);
  *(u16x8*)(d + off) = vh;
}

// Plain fp16 GEMM, m97 structure (single-buffer, 2 barriers/K-step), 2x2 wave
// tiling: C = A[M,KP] @ B[N,KP]^T + bias.
// R1: dbuf regressed. R2: 128x128 tile regressed. 64-row tiles verified best.
// CLSFIX (R5): blocks whose A-tile contains row 0 / row 2049 first combine the
// CLS split-K partials (written by the attn launch) and store those rows of
// Aatt, then s_waitcnt vmcnt(0) before staging — same-block RAW through L2;
// no other block reads those rows as A-operands. Duplicate writers (one per
// n0) store identical deterministic bytes — benign.
template <int BM, int BN, bool F16OUT, bool CLSFIX>
__global__ __launch_bounds__(256) void gemm_f16(
    const unsigned short* __restrict__ A, const unsigned short* __restrict__ B,
    const float* __restrict__ bias, void* __restrict__ Cv, int M, int N,
    int KP, unsigned short* __restrict__ Afix, const float* __restrict__ Pm,
    const float* __restrict__ Pl, const float* __restrict__ Po) {
  constexpr int BK = 64;
  __shared__ __align__(16) unsigned short As[BM * BK];
  __shared__ __align__(16) unsigned short Bs[BN * BK];
  const int t = threadIdx.x;
  const int lane = t & 63, wv = t >> 6;
  const int m0 = blockIdx.x * BM, n0 = blockIdx.y * BN;
  constexpr int WM = BM / 2, WN = BN / 2;
  constexpr int RM = WM / 16, RN = WN / 16;
  const int wm = wv & 1, wn = wv >> 1;
  const int lm = lane & 15, lq = lane >> 4;

  if constexpr (CLSFIX) {
    // rows 0 (b=0) and 2049 (b=1) of Aatt are produced HERE from partials.
    if ((m0 == 0 || m0 == 2048) && t < 64) {
      int bb = (m0 == 0) ? 0 : 1;
      unsigned short* dst = Afix + (size_t)(bb * S_LEN) * 512;
#pragma unroll
      for (int hh = 0; hh < NH; hh++) {
        int i0 = (bb * NH + hh) * 2;
        float pm0 = Pm[i0], pm1 = Pm[i0 + 1];
        float Mx = fmaxf(pm0, pm1);
        float e0 = __expf(pm0 - Mx), e1 = __expf(pm1 - Mx);
        float L = Pl[i0] * e0 + Pl[i0 + 1] * e1;
        float O = Po[(size_t)i0 * 64 + t] * e0 + Po[(size_t)(i0 + 1) * 64 + t] * e1;
        dst[hh * 64 + t] = f2h(O / L);
      }
    }
    asm volatile("s_waitcnt vmcnt(0)" ::: "memory");
  }

  f32x4 acc[RM][RN];
#pragma unroll
  for (int i = 0; i < RM; i++)
#pragma unroll
    for (int j = 0; j < RN; j++) acc[i][j] = (f32x4){0.f, 0.f, 0.f, 0.f};

  const int lr = lane >> 3;
  const int lc = (lane & 7) ^ lr;  // XOR-swizzled source chunk (bank spread)

  const unsigned* aptr[BM / 32];
#pragma unroll
  for (int p = 0; p < BM / 32; p++) {
    int ra = wv * (BM / 4) + p * 8 + lr;
    int gr = m0 + ra;
    gr = gr < M ? gr : M - 1;  // clamp source (epilogue store is guarded)
    aptr[p] = (const unsigned*)(A + (size_t)gr * KP + lc * 8);
  }
  const unsigned* bptr[BN / 32];
#pragma unroll
  for (int p = 0; p < BN / 32; p++) {
    int rb = wv * (BN / 4) + p * 8 + lr;
    bptr[p] = (const unsigned*)(B + (size_t)(n0 + rb) * KP + lc * 8);
  }

  for (int kt = 0; kt < KP; kt += BK) {
    __syncthreads();
#pragma unroll
    for (int p = 0; p < BM / 32; p++)
      gld16(aptr[p] + (kt >> 1), (unsigned*)&As[(wv * (BM / 4) + p * 8) * BK]);
#pragma unroll
    for (int p = 0; p < BN / 32; p++)
      gld16(bptr[p] + (kt >> 1), (unsigned*)&Bs[(wv * (BN / 4) + p * 8) * BK]);
    __syncthreads();

    f16x8 fa[2][RM], fb[2][RN];
#pragma unroll
    for (int kk = 0; kk < 2; kk++) {
      int ch = ((kk * 4 + lq) ^ (lm & 7)) * 8;
#pragma unroll
      for (int mi = 0; mi < RM; mi++) {
        int ra = wm * WM + mi * 16 + lm;
        fa[kk][mi] = *(const f16x8*)&As[ra * BK + ch];
      }
#pragma unroll
      for (int ni = 0; ni < RN; ni++) {
        int rb = wn * WN + ni * 16 + lm;
        fb[kk][ni] = *(const f16x8*)&Bs[rb * BK + ch];
      }
    }
#pragma unroll
    for (int kk = 0; kk < 2; kk++)
#pragma unroll
      for (int mi = 0; mi < RM; mi++)
#pragma unroll
        for (int ni = 0; ni < RN; ni++)
          acc[mi][ni] = __builtin_amdgcn_mfma_f32_16x16x32_f16(
              fa[kk][mi], fb[kk][ni], acc[mi][ni], 0, 0, 0);
  }

  // C/D layout: col=lane&15 (=n), row=(lane>>4)*4+reg (=m)  [m89/m91]
#pragma unroll
  for (int ni = 0; ni < RN; ni++) {
    int n = n0 + wn * WN + ni * 16 + lm;
    float bv = bias[n];
#pragma unroll
    for (int mi = 0; mi < RM; mi++)
#pragma unroll
      for (int r = 0; r < 4; r++) {
        int m = m0 + wm * WM + mi * 16 + lq * 4 + r;
        if (m < M) {
          float val = acc[mi][ni][r] + bv;
          if constexpr (F16OUT)
            ((unsigned short*)Cv)[(size_t)m * N + n] = f2h(val);
          else
            ((float*)Cv)[(size_t)m * N + n] = val;
        }
      }
  }
}

// MFMA flash-window attention over fp16 qkv + PARALLEL fused CLS stage 1.
// grid = (17, NH, 4):
//   qb==0  -> CLS split-K stage 1: 32 blocks (h, z): b=z>>1, half=z&1. Each
//             block runs 32 independent key-streams (wave wv x kidx=lane>>3,
//             dims split c=lane&7), lane-LOCAL online softmax (no per-iter
//             cross-key shuffles — R4's 42us serial-tail lesson), then a
//             log-tree combine. Writes (m,l,o) partials to Pm/Pl/Po.
//             Combine into Aatt rows 0/2049 happens in GEMM2's prologue.
//   qb 1..16 -> patch blocks (qc0=(qb-1)*64), R3-verified structure.
__global__ __launch_bounds__(256) void patch_attn3(
    const unsigned short* __restrict__ qkv16, unsigned short* __restrict__ Aatt,
    float* __restrict__ Pm, float* __restrict__ Pl, float* __restrict__ Po) {
  constexpr int LDK = 72;   // ushort stride for Ks (144 B rows, 16B-aligned)
  constexpr int LDT = 168;  // ushort stride for Vt/Ps
  __shared__ __align__(16) unsigned short Ks[144 * LDK];  // 20.25 KB
  __shared__ __align__(16) unsigned short Vt[64 * LDT];   // 21 KB
  __shared__ __align__(16) unsigned short Ps[64 * LDT];   // 21 KB

  const int t = threadIdx.x;
  const int lane = t & 63, wv = t >> 6;
  const int lm = lane & 15, lq = lane >> 4;
  const int qb = blockIdx.x;  // 0 = cls stage-1, 1..16 = patch
  const int h = blockIdx.y;
  const int par = blockIdx.z & 1, b = blockIdx.z >> 1;
  const unsigned short* base = qkv16 + (size_t)b * S_LEN * 1536;

  if (qb == 0) {
    // ===== CLS split-K stage 1 (half = par selects key range) =====
    const int kidx = lane >> 3, c = lane & 7, d0 = c * 8;
    const int st = wv * 8 + kidx;           // stream 0..31
    const int jbase = par * 1025;
    const int count = par ? 1024 : 1025;    // keys in this half
    float qv[8];
    {
      f16x8 qh = *(const f16x8*)(base + h * 64 + d0);
#pragma unroll
      for (int i = 0; i < 8; i++) qv[i] = (float)qh[i] * SCALE;
    }
    float m = -1e30f, l = 0.f, o[8];
#pragma unroll
    for (int i = 0; i < 8; i++) o[i] = 0.f;
    for (int it = 0; it < 33; it++) {
      int rel = it * 32 + st;
      bool valid = rel < count;
      float dp = 0.f;
      f16x8 vh;
      if (valid) {
        const unsigned short* row =
            base + (size_t)(jbase + rel) * 1536 + 512 + h * 64;
        f16x8 kh = *(const f16x8*)(row + d0);
        vh = *(const f16x8*)(row + 512 + d0);
#pragma unroll
        for (int i = 0; i < 8; i++) dp += qv[i] * (float)kh[i];
      }
      // reduce dot over the 8 dim-group lanes (bits 0..2)
#pragma unroll
      for (int off = 1; off < 8; off <<= 1) dp += __shfl_xor(dp, off, 64);
      float sv = valid ? dp : -1e30f;
      float mn = fmaxf(m, sv);
      float sc = __expf(m - mn);
      float e = valid ? __expf(sv - mn) : 0.f;
      l = l * sc + e;
#pragma unroll
      for (int i = 0; i < 8; i++)
        o[i] = o[i] * sc + (valid ? e * (float)vh[i] : 0.f);
      m = mn;
    }
    // combine the 8 kidx streams within the wave (bits 3..5), once
#pragma unroll
    for (int off = 8; off < 64; off <<= 1) {
      float m2 = __shfl_xor(m, off, 64);
      float l2 = __shfl_xor(l, off, 64);
      float mn = fmaxf(m, m2);
      float e0 = __expf(m - mn), e1 = __expf(m2 - mn);
      l = l * e0 + l2 * e1;
#pragma unroll
      for (int i = 0; i < 8; i++) {
        float o2 = __shfl_xor(o[i], off, 64);
        o[i] = o[i] * e0 + o2 * e1;
      }
      m = mn;
    }
    // cross-wave combine via LDS (reuse Ks as float scratch)
    float* SF = (float*)Ks;  // [4][64] o + [4] m + [4] l
    if (kidx == 0) {
#pragma unroll
      for (int i = 0; i < 8; i++) SF[wv * 64 + d0 + i] = o[i];
    }
    if (lane == 0) {
      SF[256 + wv] = m;
      SF[260 + wv] = l;
    }
    __syncthreads();
    if (t < 64) {
      float Mx = -1e30f;
#pragma unroll
      for (int i = 0; i < 4; i++) Mx = fmaxf(Mx, SF[256 + i]);
      float L = 0.f, O = 0.f;
#pragma unroll
      for (int i = 0; i < 4; i++) {
        float ce = __expf(SF[256 + i] - Mx);
        L += SF[260 + i] * ce;
        O += SF[i * 64 + t] * ce;
      }
      int idx = (b * NH + h) * 2 + par;
      if (t == 0) {
        Pm[idx] = Mx;
        Pl[idx] = L;
      }
      Po[(size_t)idx * 64 + t] = O;
    }
    return;
  }

  // ================= patch attention block =================
  const int qc0 = (qb - 1) * 64;

  // ---- precise zero of read-but-never-staged LDS regions (R3 win) ----
  {
    uint4 z = {0, 0, 0, 0};
    // Ks rows 129..143, cols 0..63 (QK^T reads rows up to 143): 120 x 16B
    if (t < 120) {
      int r = 129 + (t >> 3), c = (t & 7) * 8;
      *(uint4*)&Ks[r * LDK + c] = z;
    }
    // Vt cols 128..159, rows 0..63 (PV K=160; col 128 re-staged below): 256
    {
      int r = t >> 2, c = 128 + (t & 3) * 8;
      *(uint4*)&Vt[r * LDT + c] = z;
    }
    // Ps cols 144..159, rows 0..63 (softmax writes only cols 0..143): 128
    if (t < 128) {
      int r = t >> 1, c = 144 + (t & 1) * 8;
      *(uint4*)&Ps[r * LDT + c] = z;
    }
  }
  __syncthreads();

  // ---- stage K (direct fp16 copy): window rows 0..127, cls row 128 ----
  {
    int rr = t >> 4;
    int cc = (t & 15) * 4;  // 4 halves (8 B) per thread
#pragma unroll
    for (int pass = 0; pass < 8; pass++) {
      int r = pass * 16 + rr;
      int jc = qc0 - 32 + r;
      uint2 kv = {0, 0};
      if ((unsigned)jc < 1024u)
        kv = *(const uint2*)(base + (size_t)(1 + 2 * jc + par) * 1536 + 512 +
                             h * 64 + cc);
      *(uint2*)&Ks[r * LDK + cc] = kv;
    }
    if (rr == 0)
      *(uint2*)&Ks[128 * LDK + cc] =
          *(const uint2*)(base + 512 + h * 64 + cc);
  }
  // ---- stage V transposed: Vt[d][jl] via half-pair repack ----
#pragma unroll
  for (int pass = 0; pass < 4; pass++) {
    int task = pass * 256 + t;
    int jp = task >> 4;        // jl pair 0..63
    int d0 = (task & 15) * 4;  // dim base
    int jc0 = qc0 - 32 + 2 * jp;
    uint2 a = {0, 0}, c = {0, 0};
    if ((unsigned)jc0 < 1024u)
      a = *(const uint2*)(base + (size_t)(1 + 2 * jc0 + par) * 1536 + 1024 +
                          h * 64 + d0);
    if ((unsigned)(jc0 + 1) < 1024u)
      c = *(const uint2*)(base + (size_t)(1 + 2 * (jc0 + 1) + par) * 1536 +
                          1024 + h * 64 + d0);
    *(unsigned*)&Vt[(d0 + 0) * LDT + 2 * jp] = (a.x & 0xffffu) | (c.x << 16);
    *(unsigned*)&Vt[(d0 + 1) * LDT + 2 * jp] = (a.x >> 16) | (c.x & 0xffff0000u);
    *(unsigned*)&Vt[(d0 + 2) * LDT + 2 * jp] = (a.y & 0xffffu) | (c.y << 16);
    *(unsigned*)&Vt[(d0 + 3) * LDT + 2 * jp] = (a.y >> 16) | (c.y & 0xffff0000u);
  }
  if (t < 64) Vt[t * LDT + 128] = base[1024 + h * 64 + t];  // cls V col

  // ---- Q fragment: direct f16x8 loads (A-frag: m=lane&15, k=quad*8+j) ----
  const int qi = wv * 16 + lm;
  const unsigned short* qg =
      base + (size_t)(1 + 2 * (qc0 + qi) + par) * 1536 + h * 64;
  f16x8 qf[2];
  qf[0] = *(const f16x8*)&qg[lq * 8];
  qf[1] = *(const f16x8*)&qg[32 + lq * 8];
  __syncthreads();

  // ---- S = Q·K^T : 9 N-tiles of 16 cols ----
  f32x4 s[9];
#pragma unroll
  for (int nt = 0; nt < 9; nt++) s[nt] = (f32x4){0.f, 0.f, 0.f, 0.f};
#pragma unroll
  for (int nt = 0; nt < 9; nt++) {
#pragma unroll
    for (int kk = 0; kk < 2; kk++) {
      f16x8 kb = *(const f16x8*)&Ks[(nt * 16 + lm) * LDK + kk * 32 + lq * 8];
      s[nt] =
          __builtin_amdgcn_mfma_f32_16x16x32_f16(qf[kk], kb, s[nt], 0, 0, 0);
    }
  }

  // ---- masked softmax per row; SCALE applied here (post-MFMA, fp32) ----
  float L[4];
#pragma unroll
  for (int r = 0; r < 4; r++) {
    int qrow = wv * 16 + lq * 4 + r;  // query index within 64-chunk
    float sv[9];
    float mx = -1e30f;
#pragma unroll
    for (int nt = 0; nt < 9; nt++) {
      int jl = nt * 16 + lm;
      bool valid =
          (jl == 128) ||
          (jl < 128 && jl >= qrow && jl <= qrow + 64 &&
           (unsigned)(qc0 - 32 + jl) < 1024u);
      sv[nt] = valid ? s[nt][r] * SCALE : -1e30f;
      mx = fmaxf(mx, sv[nt]);
    }
#pragma unroll
    for (int off = 1; off < 16; off <<= 1)
      mx = fmaxf(mx, __shfl_xor(mx, off, 16));
    float l = 0.f;
#pragma unroll
    for (int nt = 0; nt < 9; nt++) {
      float e = __expf(sv[nt] - mx);
      l += e;
      Ps[qrow * LDT + nt * 16 + lm] = f2h(e);
    }
#pragma unroll
    for (int off = 1; off < 16; off <<= 1) l += __shfl_xor(l, off, 16);
    L[r] = l;
  }
  __syncthreads();

  // ---- O = P·V : A=Ps rows (m=query), B=Vt rows (n=d), K=160 ----
  f32x4 oa[4];
#pragma unroll
  for (int nt = 0; nt < 4; nt++) oa[nt] = (f32x4){0.f, 0.f, 0.f, 0.f};
#pragma unroll
  for (int kc = 0; kc < 5; kc++) {
    f16x8 pa = *(const f16x8*)&Ps[(wv * 16 + lm) * LDT + kc * 32 + lq * 8];
#pragma unroll
    for (int nt = 0; nt < 4; nt++) {
      f16x8 vb = *(const f16x8*)&Vt[(nt * 16 + lm) * LDT + kc * 32 + lq * 8];
      oa[nt] = __builtin_amdgcn_mfma_f32_16x16x32_f16(pa, vb, oa[nt], 0, 0, 0);
    }
  }

  // ---- epilogue: normalize, write fp16 into Aatt[*, 512] ----
#pragma unroll
  for (int r = 0; r < 4; r++) {
    float inv = 1.f / L[r];
    int qrow = wv * 16 + lq * 4 + r;
    int pp = 2 * (qc0 + qrow) + par;
    unsigned short* ab = Aatt + ((size_t)b * S_LEN + 1 + pp) * 512 + h * 64;
#pragma unroll
    for (int nt = 0; nt < 4; nt++) ab[nt * 16 + lm] = f2h(oa[nt][r] * inv);
  }
}

extern "C" void kernel_launch(void* const* d_in, const int* in_sizes, int n_in,
                              void* d_out, int out_size, void* d_ws,
                              size_t ws_size, hipStream_t stream) {
  const float* x = (const float*)d_in[0];
  const float* qkv_w = (const float*)d_in[1];
  const float* qkv_b = (const float*)d_in[2];
  const float* out_w = (const float*)d_in[3];
  const float* out_b = (const float*)d_in[4];
  float* out = (float*)d_out;

  const int M = 2 * S_LEN;  // 4098

  float* cls_pm = (float*)d_ws;                            // 32 used
  float* cls_pl = cls_pm + 512;                            // 32 used
  float* cls_po = cls_pl + 512;                            // 2048 used
  unsigned short* Xp = (unsigned short*)(cls_po + 32768);  // 4098*512 fp16
  unsigned short* Wq = Xp + (size_t)M * 512;               // 1536*512 fp16
  unsigned short* Wo = Wq + (size_t)1536 * 512;            // 512*512 fp16
  unsigned short* Aatt = Wo + (size_t)512 * 512;           // 4098*512 fp16
  unsigned short* qkv16 = Aatt + (size_t)M * 512;          // 4098*1536 fp16

  const int n0 = M * EMB;       // 2098176
  const int n1 = 1536 * EMB;    // 786432
  const int n2 = EMB * EMB;     // 262144
  int cvt_blocks = ((n0 + n1 + n2) / 8 + 255) / 256;
  cvt3_f16<<<cvt_blocks, 256, 0, stream>>>(x, Xp, n0, qkv_w, Wq, n1, out_w, Wo,
                                           n2);

  // QKV projection: fp16 GEMM K=512, fp16 output (R0-verified config)
  dim3 gq((M + 63) / 64, 1536 / 128);  // 65 x 12 = 780 blocks
  gemm_f16<64, 128, true, false><<<gq, 256, 0, stream>>>(
      Xp, Wq, qkv_b, qkv16, M, 1536, 512, nullptr, nullptr, nullptr, nullptr);

  // fused attention: cls stage-1 blocks (x==0) + patch blocks (x==1..16)
  patch_attn3<<<dim3(17, NH, 4), 256, 0, stream>>>(qkv16, Aatt, cls_pm, cls_pl,
                                                   cls_po);

  // Output projection: fp16 GEMM K=512, fp32 output; CLS combine in prologue
  dim3 go((M + 63) / 64, EMB / 64);  // 65 x 8 = 520 blocks
  gemm_f16<64, 64, false, true><<<go, 256, 0, stream>>>(
      Aatt, Wo, out_b, out, M, EMB, 512, Aatt, cls_pm, cls_pl, cls_po);
}

// Round 7
// 116.383 us; speedup vs baseline: 1.2323x; 1.0516x over previous
//
#include <hip/hip_runtime.h>
#include <math.h>

#define S_LEN 2049
#define P_LEN 2048
#define EMB 512
#define NH 8
#define HD 64
#define SCALE 0.125f

typedef _Float16 f16x8 __attribute__((ext_vector_type(8)));
typedef float f32x4 __attribute__((ext_vector_type(4)));
typedef unsigned short u16x8 __attribute__((ext_vector_type(8)));

__device__ inline unsigned short f2h(float f) {
  _Float16 h = (_Float16)f;  // RNE
  return __builtin_bit_cast(unsigned short, h);
}
__device__ inline float h2f(unsigned short u) {
  return (float)__builtin_bit_cast(_Float16, u);
}

__device__ inline float wave_sum64(float v) {
#pragma unroll
  for (int off = 32; off > 0; off >>= 1) v += __shfl_xor(v, off, 64);
  return v;
}

// async global->LDS, 16B per lane; LDS dest = wave-uniform base + lane*16
__device__ inline void gld16(const unsigned* g, unsigned* l) {
  __builtin_amdgcn_global_load_lds(
      (const __attribute__((address_space(1))) unsigned*)g,
      (__attribute__((address_space(3))) unsigned*)l, 16, 0, 0);
}

// fused fp32 -> fp16 converter for the three operands (x, qkv_w, out_w).
__global__ __launch_bounds__(256) void cvt3_f16(
    const float* __restrict__ s0, unsigned short* __restrict__ d0, int n0,
    const float* __restrict__ s1, unsigned short* __restrict__ d1, int n1,
    const float* __restrict__ s2, unsigned short* __restrict__ d2, int n2) {
  int idx = (blockIdx.x * 256 + threadIdx.x) * 8;
  const float* s;
  unsigned short* d;
  int off;
  if (idx < n0) {
    s = s0; d = d0; off = idx;
  } else if (idx < n0 + n1) {
    s = s1; d = d1; off = idx - n0;
  } else if (idx < n0 + n1 + n2) {
    s = s2; d = d2; off = idx - n0 - n1;
  } else {
    return;
  }
  float4 f0 = *(const float4*)(s + off);
  float4 f1 = *(const float4*)(s + off + 4);
  float ff[8] = {f0.x, f0.y, f0.z, f0.w, f1.x, f1.y, f1.z, f1.w};
  u16x8 vh;
#pragma unroll
  for (int e = 0; e < 8; e++) vh[e] = f2h(ff[e]);
  *(u16x8*)(d + off) = vh;
}

// Plain fp16 GEMM, m97 structure (single-buffer, 2 barriers/K-step), 2x2 wave
// tiling: C = A[M,KP] @ B[N,KP]^T + bias.
// R1: dbuf regressed. R2: 128x128 tile regressed. R6: structure churn
// regressed. 64-row tiles + 780/520 blocks is the verified optimum here.
template <int BM, int BN, bool F16OUT>
__global__ __launch_bounds__(256) void gemm_f16(
    const unsigned short* __restrict__ A, const unsigned short* __restrict__ B,
    const float* __restrict__ bias, void* __restrict__ Cv, int M, int N,
    int KP) {
  constexpr int BK = 64;
  __shared__ __align__(16) unsigned short As[BM * BK];
  __shared__ __align__(16) unsigned short Bs[BN * BK];
  const int t = threadIdx.x;
  const int lane = t & 63, wv = t >> 6;
  const int m0 = blockIdx.x * BM, n0 = blockIdx.y * BN;
  constexpr int WM = BM / 2, WN = BN / 2;
  constexpr int RM = WM / 16, RN = WN / 16;
  const int wm = wv & 1, wn = wv >> 1;
  const int lm = lane & 15, lq = lane >> 4;

  f32x4 acc[RM][RN];
#pragma unroll
  for (int i = 0; i < RM; i++)
#pragma unroll
    for (int j = 0; j < RN; j++) acc[i][j] = (f32x4){0.f, 0.f, 0.f, 0.f};

  const int lr = lane >> 3;
  const int lc = (lane & 7) ^ lr;  // XOR-swizzled source chunk (bank spread)

  const unsigned* aptr[BM / 32];
#pragma unroll
  for (int p = 0; p < BM / 32; p++) {
    int ra = wv * (BM / 4) + p * 8 + lr;
    int gr = m0 + ra;
    gr = gr < M ? gr : M - 1;  // clamp source (epilogue store is guarded)
    aptr[p] = (const unsigned*)(A + (size_t)gr * KP + lc * 8);
  }
  const unsigned* bptr[BN / 32];
#pragma unroll
  for (int p = 0; p < BN / 32; p++) {
    int rb = wv * (BN / 4) + p * 8 + lr;
    bptr[p] = (const unsigned*)(B + (size_t)(n0 + rb) * KP + lc * 8);
  }

  for (int kt = 0; kt < KP; kt += BK) {
    __syncthreads();
#pragma unroll
    for (int p = 0; p < BM / 32; p++)
      gld16(aptr[p] + (kt >> 1), (unsigned*)&As[(wv * (BM / 4) + p * 8) * BK]);
#pragma unroll
    for (int p = 0; p < BN / 32; p++)
      gld16(bptr[p] + (kt >> 1), (unsigned*)&Bs[(wv * (BN / 4) + p * 8) * BK]);
    __syncthreads();

    f16x8 fa[2][RM], fb[2][RN];
#pragma unroll
    for (int kk = 0; kk < 2; kk++) {
      int ch = ((kk * 4 + lq) ^ (lm & 7)) * 8;
#pragma unroll
      for (int mi = 0; mi < RM; mi++) {
        int ra = wm * WM + mi * 16 + lm;
        fa[kk][mi] = *(const f16x8*)&As[ra * BK + ch];
      }
#pragma unroll
      for (int ni = 0; ni < RN; ni++) {
        int rb = wn * WN + ni * 16 + lm;
        fb[kk][ni] = *(const f16x8*)&Bs[rb * BK + ch];
      }
    }
#pragma unroll
    for (int kk = 0; kk < 2; kk++)
#pragma unroll
      for (int mi = 0; mi < RM; mi++)
#pragma unroll
        for (int ni = 0; ni < RN; ni++)
          acc[mi][ni] = __builtin_amdgcn_mfma_f32_16x16x32_f16(
              fa[kk][mi], fb[kk][ni], acc[mi][ni], 0, 0, 0);
  }

  // C/D layout: col=lane&15 (=n), row=(lane>>4)*4+reg (=m)  [m89/m91]
#pragma unroll
  for (int ni = 0; ni < RN; ni++) {
    int n = n0 + wn * WN + ni * 16 + lm;
    float bv = bias[n];
#pragma unroll
    for (int mi = 0; mi < RM; mi++)
#pragma unroll
      for (int r = 0; r < 4; r++) {
        int m = m0 + wm * WM + mi * 16 + lq * 4 + r;
        if (m < M) {
          float val = acc[mi][ni][r] + bv;
          if constexpr (F16OUT)
            ((unsigned short*)Cv)[(size_t)m * N + n] = f2h(val);
          else
            ((float*)Cv)[(size_t)m * N + n] = val;
        }
      }
  }
}

// MFMA flash-window attention over fp16 qkv. Staging is pure copy (no
// conversion); SCALE applied post-MFMA on fp32 logits.
// Precise zeroing (R3 win): only read-but-never-staged regions.
// Blocks with (qb==0 && par==0) also run the CLS split-K combine with their
// first 64 threads at the end. R7 change: combine is PREFETCH-ALL (32
// independent loads into registers, unrolled/static -> no scratch) then
// two-pass max/sum — removes the 32-step serial dependent-load tail.
__global__ __launch_bounds__(256) void patch_attn3(
    const unsigned short* __restrict__ qkv16, unsigned short* __restrict__ Aatt,
    const float* __restrict__ Pm, const float* __restrict__ Pl,
    const float* __restrict__ Po) {
  constexpr int LDK = 72;   // ushort stride for Ks (144 B rows, 16B-aligned)
  constexpr int LDT = 168;  // ushort stride for Vt/Ps
  __shared__ __align__(16) unsigned short Ks[144 * LDK];  // 20.25 KB
  __shared__ __align__(16) unsigned short Vt[64 * LDT];   // 21 KB
  __shared__ __align__(16) unsigned short Ps[64 * LDT];   // 21 KB

  const int t = threadIdx.x;
  const int lane = t & 63, wv = t >> 6;
  const int lm = lane & 15, lq = lane >> 4;
  const int qb = blockIdx.x;  // 0..15
  const int h = blockIdx.y;
  const int par = blockIdx.z & 1, b = blockIdx.z >> 1;
  const unsigned short* base = qkv16 + (size_t)b * S_LEN * 1536;
  const int qc0 = qb * 64;

  // ---- precise zero of read-but-never-staged LDS regions (R3 win) ----
  {
    uint4 z = {0, 0, 0, 0};
    // Ks rows 129..143, cols 0..63 (QK^T reads rows up to 143): 120 x 16B
    if (t < 120) {
      int r = 129 + (t >> 3), c = (t & 7) * 8;
      *(uint4*)&Ks[r * LDK + c] = z;
    }
    // Vt cols 128..159, rows 0..63 (PV K=160; col 128 re-staged below): 256
    {
      int r = t >> 2, c = 128 + (t & 3) * 8;
      *(uint4*)&Vt[r * LDT + c] = z;
    }
    // Ps cols 144..159, rows 0..63 (softmax writes only cols 0..143): 128
    if (t < 128) {
      int r = t >> 1, c = 144 + (t & 1) * 8;
      *(uint4*)&Ps[r * LDT + c] = z;
    }
  }
  __syncthreads();

  // ---- stage K (direct fp16 copy): window rows 0..127, cls row 128 ----
  {
    int rr = t >> 4;
    int cc = (t & 15) * 4;  // 4 halves (8 B) per thread
#pragma unroll
    for (int pass = 0; pass < 8; pass++) {
      int r = pass * 16 + rr;
      int jc = qc0 - 32 + r;
      uint2 kv = {0, 0};
      if ((unsigned)jc < 1024u)
        kv = *(const uint2*)(base + (size_t)(1 + 2 * jc + par) * 1536 + 512 +
                             h * 64 + cc);
      *(uint2*)&Ks[r * LDK + cc] = kv;
    }
    if (rr == 0)
      *(uint2*)&Ks[128 * LDK + cc] =
          *(const uint2*)(base + 512 + h * 64 + cc);
  }
  // ---- stage V transposed: Vt[d][jl] via half-pair repack ----
#pragma unroll
  for (int pass = 0; pass < 4; pass++) {
    int task = pass * 256 + t;
    int jp = task >> 4;        // jl pair 0..63
    int d0 = (task & 15) * 4;  // dim base
    int jc0 = qc0 - 32 + 2 * jp;
    uint2 a = {0, 0}, c = {0, 0};
    if ((unsigned)jc0 < 1024u)
      a = *(const uint2*)(base + (size_t)(1 + 2 * jc0 + par) * 1536 + 1024 +
                          h * 64 + d0);
    if ((unsigned)(jc0 + 1) < 1024u)
      c = *(const uint2*)(base + (size_t)(1 + 2 * (jc0 + 1) + par) * 1536 +
                          1024 + h * 64 + d0);
    *(unsigned*)&Vt[(d0 + 0) * LDT + 2 * jp] = (a.x & 0xffffu) | (c.x << 16);
    *(unsigned*)&Vt[(d0 + 1) * LDT + 2 * jp] = (a.x >> 16) | (c.x & 0xffff0000u);
    *(unsigned*)&Vt[(d0 + 2) * LDT + 2 * jp] = (a.y & 0xffffu) | (c.y << 16);
    *(unsigned*)&Vt[(d0 + 3) * LDT + 2 * jp] = (a.y >> 16) | (c.y & 0xffff0000u);
  }
  if (t < 64) Vt[t * LDT + 128] = base[1024 + h * 64 + t];  // cls V col

  // ---- Q fragment: direct f16x8 loads (A-frag: m=lane&15, k=quad*8+j) ----
  const int qi = wv * 16 + lm;
  const unsigned short* qg =
      base + (size_t)(1 + 2 * (qc0 + qi) + par) * 1536 + h * 64;
  f16x8 qf[2];
  qf[0] = *(const f16x8*)&qg[lq * 8];
  qf[1] = *(const f16x8*)&qg[32 + lq * 8];
  __syncthreads();

  // ---- S = Q·K^T : 9 N-tiles of 16 cols ----
  f32x4 s[9];
#pragma unroll
  for (int nt = 0; nt < 9; nt++) s[nt] = (f32x4){0.f, 0.f, 0.f, 0.f};
#pragma unroll
  for (int nt = 0; nt < 9; nt++) {
#pragma unroll
    for (int kk = 0; kk < 2; kk++) {
      f16x8 kb = *(const f16x8*)&Ks[(nt * 16 + lm) * LDK + kk * 32 + lq * 8];
      s[nt] =
          __builtin_amdgcn_mfma_f32_16x16x32_f16(qf[kk], kb, s[nt], 0, 0, 0);
    }
  }

  // ---- masked softmax per row; SCALE applied here (post-MFMA, fp32) ----
  float L[4];
#pragma unroll
  for (int r = 0; r < 4; r++) {
    int qrow = wv * 16 + lq * 4 + r;  // query index within 64-chunk
    float sv[9];
    float mx = -1e30f;
#pragma unroll
    for (int nt = 0; nt < 9; nt++) {
      int jl = nt * 16 + lm;
      bool valid =
          (jl == 128) ||
          (jl < 128 && jl >= qrow && jl <= qrow + 64 &&
           (unsigned)(qc0 - 32 + jl) < 1024u);
      sv[nt] = valid ? s[nt][r] * SCALE : -1e30f;
      mx = fmaxf(mx, sv[nt]);
    }
#pragma unroll
    for (int off = 1; off < 16; off <<= 1)
      mx = fmaxf(mx, __shfl_xor(mx, off, 16));
    float l = 0.f;
#pragma unroll
    for (int nt = 0; nt < 9; nt++) {
      float e = __expf(sv[nt] - mx);
      l += e;
      Ps[qrow * LDT + nt * 16 + lm] = f2h(e);
    }
#pragma unroll
    for (int off = 1; off < 16; off <<= 1) l += __shfl_xor(l, off, 16);
    L[r] = l;
  }
  __syncthreads();

  // ---- O = P·V : A=Ps rows (m=query), B=Vt rows (n=d), K=160 ----
  f32x4 oa[4];
#pragma unroll
  for (int nt = 0; nt < 4; nt++) oa[nt] = (f32x4){0.f, 0.f, 0.f, 0.f};
#pragma unroll
  for (int kc = 0; kc < 5; kc++) {
    f16x8 pa = *(const f16x8*)&Ps[(wv * 16 + lm) * LDT + kc * 32 + lq * 8];
#pragma unroll
    for (int nt = 0; nt < 4; nt++) {
      f16x8 vb = *(const f16x8*)&Vt[(nt * 16 + lm) * LDT + kc * 32 + lq * 8];
      oa[nt] = __builtin_amdgcn_mfma_f32_16x16x32_f16(pa, vb, oa[nt], 0, 0, 0);
    }
  }

  // ---- epilogue: normalize, write fp16 into Aatt[*, 512] ----
#pragma unroll
  for (int r = 0; r < 4; r++) {
    float inv = 1.f / L[r];
    int qrow = wv * 16 + lq * 4 + r;
    int pp = 2 * (qc0 + qrow) + par;
    unsigned short* ab = Aatt + ((size_t)b * S_LEN + 1 + pp) * 512 + h * 64;
#pragma unroll
    for (int nt = 0; nt < 4; nt++) ab[nt * 16 + lm] = f2h(oa[nt][r] * inv);
  }

  // ---- fused CLS split-K combine: prefetch-all then two-pass (R7) ----
  if (qb == 0 && par == 0 && t < 64) {
    const int ib = (b * NH + h) * 32;
    float pm[32], pl[32], po[32];
#pragma unroll
    for (int ck = 0; ck < 32; ck++) {
      pm[ck] = Pm[ib + ck];
      pl[ck] = Pl[ib + ck];
      po[ck] = Po[(size_t)(ib + ck) * 64 + t];
    }
    float Mx = -1e30f;
#pragma unroll
    for (int ck = 0; ck < 32; ck++) Mx = fmaxf(Mx, pm[ck]);
    float L2 = 0.f, O2 = 0.f;
#pragma unroll
    for (int ck = 0; ck < 32; ck++) {
      float e = __expf(pm[ck] - Mx);
      L2 += pl[ck] * e;
      O2 += po[ck] * e;
    }
    Aatt[(size_t)b * S_LEN * 512 + h * HD + t] = f2h(O2 / L2);
  }
}

// CLS attention, split-K stage 1 (fp16 qkv inputs).
__global__ __launch_bounds__(256) void cls_part_k(
    const unsigned short* __restrict__ qkv16, float* __restrict__ Pm,
    float* __restrict__ Pl, float* __restrict__ Po) {
  const int lane = threadIdx.x & 63;
  const int wv = threadIdx.x >> 6;
  const int ck = blockIdx.x;
  const int h = blockIdx.y;
  const int b = blockIdx.z;
  const unsigned short* base = qkv16 + (size_t)b * S_LEN * 1536;
  float qd = h2f(base[h * 64 + lane]) * SCALE;

  int c0 = ck * 64;
  int cend = (ck == 31) ? S_LEN : c0 + 64;

  float m = -1e30f, l = 0.f, o = 0.f;
  for (int j = c0 + wv; j < cend; j += 4) {
    const unsigned short* krow = base + (size_t)j * 1536 + 512 + h * 64;
    float kv = h2f(krow[lane]);
    float vv = h2f(krow[512 + lane]);
    float s = wave_sum64(qd * kv);
    float mn = fmaxf(m, s);
    float e0 = __expf(m - mn);
    float e1 = __expf(s - mn);
    l = l * e0 + e1;
    o = o * e0 + e1 * vv;
    m = mn;
  }

  __shared__ float sm[4], sl[4], so[4][64];
  if (lane == 0) {
    sm[wv] = m;
    sl[wv] = l;
  }
  so[wv][lane] = o;
  __syncthreads();
  if (wv == 0) {
    float M = -1e30f;
#pragma unroll
    for (int i = 0; i < 4; i++) M = fmaxf(M, sm[i]);
    float L = 0.f, O = 0.f;
#pragma unroll
    for (int i = 0; i < 4; i++) {
      float c = __expf(sm[i] - M);
      L += sl[i] * c;
      O += so[i][lane] * c;
    }
    int idx = (b * NH + h) * 32 + ck;
    if (lane == 0) {
      Pm[idx] = M;
      Pl[idx] = L;
    }
    Po[(size_t)idx * 64 + lane] = O;
  }
}

extern "C" void kernel_launch(void* const* d_in, const int* in_sizes, int n_in,
                              void* d_out, int out_size, void* d_ws,
                              size_t ws_size, hipStream_t stream) {
  const float* x = (const float*)d_in[0];
  const float* qkv_w = (const float*)d_in[1];
  const float* qkv_b = (const float*)d_in[2];
  const float* out_w = (const float*)d_in[3];
  const float* out_b = (const float*)d_in[4];
  float* out = (float*)d_out;

  const int M = 2 * S_LEN;  // 4098

  float* cls_pm = (float*)d_ws;                            // 512
  float* cls_pl = cls_pm + 512;                            // 512
  float* cls_po = cls_pl + 512;                            // 32768
  unsigned short* Xp = (unsigned short*)(cls_po + 32768);  // 4098*512 fp16
  unsigned short* Wq = Xp + (size_t)M * 512;               // 1536*512 fp16
  unsigned short* Wo = Wq + (size_t)1536 * 512;            // 512*512 fp16
  unsigned short* Aatt = Wo + (size_t)512 * 512;           // 4098*512 fp16
  unsigned short* qkv16 = Aatt + (size_t)M * 512;          // 4098*1536 fp16

  const int n0 = M * EMB;       // 2098176
  const int n1 = 1536 * EMB;    // 786432
  const int n2 = EMB * EMB;     // 262144
  int cvt_blocks = ((n0 + n1 + n2) / 8 + 255) / 256;
  cvt3_f16<<<cvt_blocks, 256, 0, stream>>>(x, Xp, n0, qkv_w, Wq, n1, out_w, Wo,
                                           n2);

  // QKV projection: fp16 GEMM K=512, fp16 output (R0-verified config)
  dim3 gq((M + 63) / 64, 1536 / 128);  // 65 x 12 = 780 blocks
  gemm_f16<64, 128, true><<<gq, 256, 0, stream>>>(Xp, Wq, qkv_b, qkv16, M,
                                                  1536, 512);

  cls_part_k<<<dim3(32, NH, 2), 256, 0, stream>>>(qkv16, cls_pm, cls_pl,
                                                  cls_po);
  patch_attn3<<<dim3(16, NH, 4), 256, 0, stream>>>(qkv16, Aatt, cls_pm, cls_pl,
                                                   cls_po);

  // Output projection: fp16 GEMM K=512, fp32 output (R0-verified config)
  dim3 go((M + 63) / 64, EMB / 64);  // 65 x 8 = 520 blocks
  gemm_f16<64, 64, false><<<go, 256, 0, stream>>>(Aatt, Wo, out_b, out, M, EMB,
                                                  512);
}